// Round 1
// baseline (17953.888 us; speedup 1.0000x reference)
//
#include <hip/hip_runtime.h>
#include <math.h>

// Problem constants (match reference setup_inputs)
#define BATCH 512
#define TT    128
#define FF    64
#define UU    1024
#define ZZ    4096   // 4*UU
#define OS    32
#define KTOT  1088   // FF + UU

__device__ __forceinline__ float sigf(float x) { return 1.0f / (1.0f + expf(-x)); }

__global__ void zero_f4(float4* p, int n4) {
    int i = blockIdx.x * blockDim.x + threadIdx.x;
    if (i < n4) p[i] = make_float4(0.f, 0.f, 0.f, 0.f);
}

// One LSTM cell step, fused GEMM + gates.
// z[b, :] = x[b,:] @ Wk + h[b,:] @ Wr + bias ; gates -> c,h update.
// Block: 256 threads computes BM=32 batch rows x BU=32 units (x 4 gates = 128 cols).
// grid.x = 512/32 = 16 batch tiles, grid.y = 1024/32 = 32 unit tiles.
__global__ __launch_bounds__(256) void lstm_cell_step(
    const float* __restrict__ x, int xstride,     // x row b at x + b*xstride, FF cols
    const float* __restrict__ h_in,               // [BATCH][UU]
    float* __restrict__ h_out,                    // [BATCH][UU]
    float* __restrict__ c,                        // [BATCH][UU], in-place
    const float* __restrict__ Wk,                 // [FF][ZZ]
    const float* __restrict__ Wr,                 // [UU][ZZ]
    const float* __restrict__ bias)               // [ZZ]
{
    __shared__ float At[32][36];    // A^T: [k][row], pad 36 keeps float4 reads aligned
    __shared__ float Wt[32][128];   // [k][gate*32 + u_local]

    const int t  = threadIdx.x;
    const int tx = t & 31;   // unit within tile
    const int ty = t >> 5;   // row group (4 rows each)
    const int r0 = blockIdx.x * 32;
    const int u0 = blockIdx.y * 32;

    float acc[4][4];  // [row][gate]
    #pragma unroll
    for (int i = 0; i < 4; i++)
        #pragma unroll
        for (int g = 0; g < 4; g++) acc[i][g] = 0.f;

    // A-chunk load mapping: each thread loads one float4
    const int ar = t >> 3;        // row 0..31
    const int ak = (t & 7) * 4;   // k offset 0,4,...,28

    for (int ko = 0; ko < KTOT; ko += 32) {
        // ---- stage A (x for ko<64, h afterwards) ----
        float4 av;
        if (ko < FF) {
            const float* p = x + (size_t)(r0 + ar) * xstride + ko + ak;
            av = *(const float4*)p;
        } else {
            const float* p = h_in + (size_t)(r0 + ar) * UU + (ko - FF) + ak;
            av = *(const float4*)p;
        }
        At[ak + 0][ar] = av.x;
        At[ak + 1][ar] = av.y;
        At[ak + 2][ar] = av.z;
        At[ak + 3][ar] = av.w;

        // ---- stage W: rows ko..ko+31 of [Wk;Wr], cols {g*1024 + u0..u0+31} ----
        #pragma unroll
        for (int i = 0; i < 4; i++) {
            int fi = t + i * 256;        // float4 index 0..1023
            int kk = fi >> 5;            // 32 float4 per k-row
            int c4 = fi & 31;
            int g  = c4 >> 3;            // gate
            int ul = (c4 & 7) * 4;       // local unit, multiple of 4
            int krow = ko + kk;
            const float* wrow = (krow < FF) ? (Wk + (size_t)krow * ZZ)
                                            : (Wr + (size_t)(krow - FF) * ZZ);
            float4 wv = *(const float4*)(wrow + g * UU + u0 + ul);
            *(float4*)&Wt[kk][c4 * 4] = wv;
        }
        __syncthreads();

        // ---- FMA over this K chunk ----
        #pragma unroll 8
        for (int kk = 0; kk < 32; kk++) {
            float4 a = *(const float4*)&At[kk][ty * 4];
            float w0 = Wt[kk][tx];
            float w1 = Wt[kk][32 + tx];
            float w2 = Wt[kk][64 + tx];
            float w3 = Wt[kk][96 + tx];
            acc[0][0] += a.x * w0; acc[1][0] += a.y * w0; acc[2][0] += a.z * w0; acc[3][0] += a.w * w0;
            acc[0][1] += a.x * w1; acc[1][1] += a.y * w1; acc[2][1] += a.z * w1; acc[3][1] += a.w * w1;
            acc[0][2] += a.x * w2; acc[1][2] += a.y * w2; acc[2][2] += a.z * w2; acc[3][2] += a.w * w2;
            acc[0][3] += a.x * w3; acc[1][3] += a.y * w3; acc[2][3] += a.z * w3; acc[3][3] += a.w * w3;
        }
        __syncthreads();
    }

    // ---- gates epilogue ----
    const int ug = u0 + tx;
    const float bi = bias[ug];
    const float bf = bias[UU + ug];
    const float bg = bias[2 * UU + ug];
    const float bo = bias[3 * UU + ug];
    #pragma unroll
    for (int j = 0; j < 4; j++) {
        const int bb = r0 + ty * 4 + j;
        const size_t idx = (size_t)bb * UU + ug;
        float zi = acc[j][0] + bi;
        float zf = acc[j][1] + bf;
        float zg = acc[j][2] + bg;
        float zo = acc[j][3] + bo;
        float cold = c[idx];
        float cn = sigf(zf) * cold + sigf(zi) * tanhf(zg);
        c[idx] = cn;
        h_out[idx] = sigf(zo) * tanhf(cn);
    }
}

// pred[b,:] = h[b,:] @ Wd + bd ; also writes out[b, s, :] (outp pre-offset by s*FF)
__global__ __launch_bounds__(256) void dense_out(
    const float* __restrict__ h,    // [BATCH][UU]
    const float* __restrict__ Wd,   // [UU][FF]
    const float* __restrict__ bd,   // [FF]
    float* __restrict__ pred,       // [BATCH][FF]
    float* __restrict__ outp)       // out + s*FF ; stride OS*FF per batch row
{
    __shared__ float red[4][64];
    const int t  = threadIdx.x;
    const int f  = t & 63;
    const int ks = t >> 6;          // 0..3, K slice of 256
    const int bb = blockIdx.x;

    const float* hrow = h + (size_t)bb * UU + ks * 256;
    const float* wp   = Wd + (size_t)(ks * 256) * FF + f;
    float s = 0.f;
    #pragma unroll 8
    for (int k = 0; k < 256; k++) s += hrow[k] * wp[(size_t)k * FF];
    red[ks][f] = s;
    __syncthreads();
    if (ks == 0) {
        float v = red[0][f] + red[1][f] + red[2][f] + red[3][f] + bd[f];
        pred[(size_t)bb * FF + f] = v;
        outp[(size_t)bb * OS * FF + f] = v;
    }
}

extern "C" void kernel_launch(void* const* d_in, const int* in_sizes, int n_in,
                              void* d_out, int out_size, void* d_ws, size_t ws_size,
                              hipStream_t stream) {
    const float* inputs = (const float*)d_in[0];   // [B][T][F]
    const float* Wk     = (const float*)d_in[1];   // [F][4U]
    const float* Wr     = (const float*)d_in[2];   // [U][4U]
    const float* bias   = (const float*)d_in[3];   // [4U]
    const float* Wd     = (const float*)d_in[4];   // [U][F]
    const float* bd     = (const float*)d_in[5];   // [F]
    float* out = (float*)d_out;                    // [B][OS][F]

    // workspace layout: h0 | c | h1 | pred  (h0,c contiguous for one zero pass)
    float* h0   = (float*)d_ws;
    float* cbuf = h0 + (size_t)BATCH * UU;
    float* h1   = cbuf + (size_t)BATCH * UU;
    float* pred = h1 + (size_t)BATCH * UU;

    // zero h0 and c (ws is poisoned before every call)
    {
        int n4 = (2 * BATCH * UU) / 4;
        zero_f4<<<(n4 + 255) / 256, 256, 0, stream>>>((float4*)h0, n4);
    }

    dim3 cgrid(BATCH / 32, UU / 32);   // 16 x 32 = 512 blocks
    dim3 cblk(256);

    float* hc = h0;
    float* hn = h1;

    // warmup over the input window
    for (int t = 0; t < TT; t++) {
        lstm_cell_step<<<cgrid, cblk, 0, stream>>>(inputs + (size_t)t * FF, TT * FF,
                                                   hc, hn, cbuf, Wk, Wr, bias);
        float* tmp = hc; hc = hn; hn = tmp;
    }

    // first prediction -> out[:, 0, :]
    dense_out<<<BATCH, 256, 0, stream>>>(hc, Wd, bd, pred, out);

    // autoregressive decode
    for (int s = 1; s < OS; s++) {
        lstm_cell_step<<<cgrid, cblk, 0, stream>>>(pred, FF, hc, hn, cbuf, Wk, Wr, bias);
        float* tmp = hc; hc = hn; hn = tmp;
        dense_out<<<BATCH, 256, 0, stream>>>(hc, Wd, bd, pred, out + (size_t)s * FF);
    }
}

// Round 2
// 12389.168 us; speedup vs baseline: 1.4492x; 1.4492x over previous
//
#include <hip/hip_runtime.h>
#include <math.h>

#define BATCH 512
#define TT    128
#define FF    64
#define UU    1024
#define ZZ    4096
#define OS    32
#define KTOT  1088
#define NCHUNK 34

typedef __bf16 bf16x8 __attribute__((ext_vector_type(8)));
typedef float f32x4 __attribute__((ext_vector_type(4)));

__device__ __forceinline__ float sigf(float x) { return 1.0f / (1.0f + expf(-x)); }

// async global->LDS, 16B per lane; LDS dest = wave-uniform base + lane*16
__device__ __forceinline__ void async_cp16(void* lds, const void* g) {
    __builtin_amdgcn_global_load_lds(
        (const __attribute__((address_space(1))) void*)g,
        (__attribute__((address_space(3))) void*)lds, 16, 0, 0);
}

// ---------------------------------------------------------------------------
// W precompute: [Wk;Wr] (1088 x 4096 fp32) -> W^T bf16 hi/lo, gate-interleaved
// columns: n' = 4*u + g  (g in i,f,g,o order), laid out [4096 n'][1088 k].
// ---------------------------------------------------------------------------
__global__ __launch_bounds__(256) void wconv(
    const float* __restrict__ Wk, const float* __restrict__ Wr,
    __bf16* __restrict__ WhT, __bf16* __restrict__ WlT)
{
    __shared__ float T[32][129];
    const int k0 = blockIdx.x * 32;   // 34 blocks
    const int n0 = blockIdx.y * 128;  // 32 panels
    const int u0 = n0 >> 2;
    const int t = threadIdx.x;
    #pragma unroll
    for (int i = 0; i < 16; ++i) {
        int idx = t + i * 256;                  // k(32) x u(32) x g(4)
        int u = idx & 31, k = (idx >> 5) & 31, g = idx >> 10;
        int krow = k0 + k;
        int col = g * UU + u0 + u;
        float wv = (krow < FF) ? Wk[(size_t)krow * ZZ + col]
                               : Wr[(size_t)(krow - FF) * ZZ + col];
        T[k][u * 4 + g] = wv;
    }
    __syncthreads();
    #pragma unroll
    for (int i = 0; i < 16; ++i) {
        int idx = t + i * 256;
        int k = idx & 31, np = idx >> 5;        // np 0..127
        float wv = T[k][np];
        __bf16 hi = (__bf16)wv;
        size_t o = (size_t)(n0 + np) * KTOT + k0 + k;
        WhT[o] = hi;
        WlT[o] = (__bf16)(wv - (float)hi);
    }
}

// ---------------------------------------------------------------------------
// init: zero h0(hi,lo) + c (4MB contiguous), convert x_0 slice to bf16 hi/lo
// ---------------------------------------------------------------------------
__global__ __launch_bounds__(256) void init_k(
    uint4* __restrict__ zbase, const float* __restrict__ x0,
    __bf16* __restrict__ xh, __bf16* __restrict__ xl)
{
    const int b = blockIdx.x, t = threadIdx.x;
    if (b < 1024) {
        zbase[(size_t)b * 256 + t] = make_uint4(0u, 0u, 0u, 0u);
    } else {
        int e = (b - 1024) * 256 + t;
        if (e < BATCH * FF) {
            int bb = e >> 6, f = e & 63;
            float v = x0[(size_t)bb * (TT * FF) + f];
            __bf16 hi = (__bf16)v;
            xh[e] = hi;
            xl[e] = (__bf16)(v - (float)hi);
        }
    }
}

// ---------------------------------------------------------------------------
// Fused LSTM cell step: z = [x|h] @ W + bias via split-bf16 3-term MFMA,
// gates in fp32, writes c (fp32, in-place) and h as bf16 hi/lo.
// Block: 256 thr (4 waves), tile BM=64 rows x BN=128 n'-cols (= 32 units x 4 gates).
// Grid: (512/64, 4096/128) = (8, 32) = 256 blocks.
// ---------------------------------------------------------------------------
__global__ __launch_bounds__(256) void lstm_cell_mfma(
    const __bf16* __restrict__ xh, const __bf16* __restrict__ xl,   // [512][64]
    const __bf16* __restrict__ hh, const __bf16* __restrict__ hl,   // [512][1024]
    __bf16* __restrict__ hho, __bf16* __restrict__ hlo_,            // [512][1024]
    float* __restrict__ c,                                          // [512][1024]
    const __bf16* __restrict__ WhT, const __bf16* __restrict__ WlT, // [4096][1088]
    const float* __restrict__ bias,                                 // [4096] natural order
    const float* __restrict__ xnext,                                // next x_t slice (or null)
    __bf16* __restrict__ xnh, __bf16* __restrict__ xnl)
{
    __shared__ union {
        struct { __bf16 ah[64 * 32]; __bf16 al[64 * 32];
                 __bf16 wh[128 * 32]; __bf16 wl[128 * 32]; } s;   // 24576 B
        float z[64 * 132];                                        // 33792 B
    } sm;

    const int t = threadIdx.x;
    const int lane = t & 63;
    const int w = t >> 6;                 // wave 0..3
    const int r0 = blockIdx.x * 64;       // batch row base
    const int n0 = blockIdx.y * 128;      // n' base
    const int u0 = n0 >> 2;               // unit base (32 units per block)

    f32x4 acc[4][2];
    #pragma unroll
    for (int i = 0; i < 4; ++i)
        #pragma unroll
        for (int j = 0; j < 2; ++j) acc[i][j] = (f32x4){0.f, 0.f, 0.f, 0.f};

    const int lr = lane >> 2;        // staging row within 16-row group
    const int lk = (lane & 3) * 8;   // staging k element offset
    const int q8 = (lane >> 4) * 8;  // MFMA quad k-offset
    const int l15 = lane & 15;

    for (int ch = 0; ch < NCHUNK; ++ch) {
        const int ko = ch * 32;
        const __bf16 *ah, *al; int stride, aoff;
        if (ch < 2) { ah = xh; al = xl; stride = FF; aoff = ko; }
        else        { ah = hh; al = hl; stride = UU; aoff = ko - FF; }

        // ---- stage A (64x32 bf16, row-major, per-wave 16 rows) ----
        {
            size_t go = (size_t)(r0 + w * 16 + lr) * stride + aoff + lk;
            async_cp16(&sm.s.ah[w * 512], ah + go);
            async_cp16(&sm.s.al[w * 512], al + go);
        }
        // ---- stage W^T (128x32 bf16, per-wave 32 rows in 2 issues) ----
        #pragma unroll
        for (int j = 0; j < 2; ++j) {
            int row = w * 32 + j * 16 + lr;
            size_t go = (size_t)(n0 + row) * KTOT + ko + lk;
            async_cp16(&sm.s.wh[(w * 32 + j * 16) * 32], WhT + go);
            async_cp16(&sm.s.wl[(w * 32 + j * 16) * 32], WlT + go);
        }
        __syncthreads();

        // ---- fragments ----
        bf16x8 afh[4], afl[4], wfh[2], wfl[2];
        #pragma unroll
        for (int mt = 0; mt < 4; ++mt) {
            afh[mt] = *(const bf16x8*)&sm.s.ah[(mt * 16 + l15) * 32 + q8];
            afl[mt] = *(const bf16x8*)&sm.s.al[(mt * 16 + l15) * 32 + q8];
        }
        #pragma unroll
        for (int nt = 0; nt < 2; ++nt) {
            int nr = (w * 2 + nt) * 16 + l15;
            wfh[nt] = *(const bf16x8*)&sm.s.wh[nr * 32 + q8];
            wfl[nt] = *(const bf16x8*)&sm.s.wl[nr * 32 + q8];
        }
        // ---- 3-term split-bf16 MFMA ----
        #pragma unroll
        for (int mt = 0; mt < 4; ++mt)
            #pragma unroll
            for (int nt = 0; nt < 2; ++nt) {
                f32x4 a = acc[mt][nt];
                a = __builtin_amdgcn_mfma_f32_16x16x32_bf16(afh[mt], wfh[nt], a, 0, 0, 0);
                a = __builtin_amdgcn_mfma_f32_16x16x32_bf16(afh[mt], wfl[nt], a, 0, 0, 0);
                a = __builtin_amdgcn_mfma_f32_16x16x32_bf16(afl[mt], wfh[nt], a, 0, 0, 0);
                acc[mt][nt] = a;
            }
        __syncthreads();
    }

    // ---- epilogue: C-frag (col=lane&15, row=(lane>>4)*4+r) -> LDS z tile ----
    {
        const int q = lane >> 4;
        #pragma unroll
        for (int mt = 0; mt < 4; ++mt)
            #pragma unroll
            for (int nt = 0; nt < 2; ++nt) {
                int nloc = (w * 2 + nt) * 16 + l15;
                #pragma unroll
                for (int r = 0; r < 4; ++r) {
                    int m = mt * 16 + q * 4 + r;
                    sm.z[m * 132 + nloc] = acc[mt][nt][r];
                }
            }
    }
    __syncthreads();

    // ---- gates: each thread 8 (m,u) pairs; z cols 4u+{0,1,2,3} = (i,f,g,o) ----
    {
        const int ul = t & 31;
        const int uu = u0 + ul;
        const float bi = bias[uu], bf_ = bias[UU + uu];
        const float bg = bias[2 * UU + uu], bo = bias[3 * UU + uu];
        #pragma unroll
        for (int rep = 0; rep < 8; ++rep) {
            int m = (t >> 5) * 8 + rep;
            float4 zg = *(const float4*)&sm.z[m * 132 + ul * 4];
            size_t idx = (size_t)(r0 + m) * UU + uu;
            float cn = sigf(zg.y + bf_) * c[idx] + sigf(zg.x + bi) * tanhf(zg.z + bg);
            c[idx] = cn;
            float hv = sigf(zg.w + bo) * tanhf(cn);
            __bf16 hi = (__bf16)hv;
            hho[idx] = hi;
            hlo_[idx] = (__bf16)(hv - (float)hi);
        }
    }

    // ---- convert next warmup x slice (grid-strided across 256 blocks) ----
    if (xnext != nullptr && t < 128) {
        int e = (blockIdx.y * 8 + blockIdx.x) * 128 + t;
        int bb = e >> 6, f = e & 63;
        float v = xnext[(size_t)bb * (TT * FF) + f];
        __bf16 hi = (__bf16)v;
        xnh[e] = hi;
        xnl[e] = (__bf16)(v - (float)hi);
    }
}

// ---------------------------------------------------------------------------
// pred = h @ Wd + bd ; writes fp32 out slice + pred as bf16 hi/lo
// ---------------------------------------------------------------------------
__global__ __launch_bounds__(256) void dense_out(
    const __bf16* __restrict__ hh, const __bf16* __restrict__ hl,
    const float* __restrict__ Wd, const float* __restrict__ bd,
    __bf16* __restrict__ ph, __bf16* __restrict__ pl,
    float* __restrict__ outp)
{
    __shared__ float red[4][64];
    const int t = threadIdx.x, f = t & 63, ks = t >> 6, bb = blockIdx.x;
    const __bf16* hrh = hh + (size_t)bb * UU + ks * 256;
    const __bf16* hrl = hl + (size_t)bb * UU + ks * 256;
    const float* wp = Wd + (size_t)(ks * 256) * FF + f;
    float s = 0.f;
    #pragma unroll 8
    for (int k = 0; k < 256; ++k)
        s += ((float)hrh[k] + (float)hrl[k]) * wp[(size_t)k * FF];
    red[ks][f] = s;
    __syncthreads();
    if (ks == 0) {
        float v = red[0][f] + red[1][f] + red[2][f] + red[3][f] + bd[f];
        outp[(size_t)bb * (OS * FF) + f] = v;
        __bf16 hi = (__bf16)v;
        ph[bb * FF + f] = hi;
        pl[bb * FF + f] = (__bf16)(v - (float)hi);
    }
}

extern "C" void kernel_launch(void* const* d_in, const int* in_sizes, int n_in,
                              void* d_out, int out_size, void* d_ws, size_t ws_size,
                              hipStream_t stream) {
    const float* inputs = (const float*)d_in[0];   // [512][128][64]
    const float* Wk     = (const float*)d_in[1];   // [64][4096]
    const float* Wr     = (const float*)d_in[2];   // [1024][4096]
    const float* bias   = (const float*)d_in[3];   // [4096]
    const float* Wd     = (const float*)d_in[4];   // [1024][64]
    const float* bd     = (const float*)d_in[5];   // [64]
    float* out = (float*)d_out;                    // [512][32][64]

    char* ws = (char*)d_ws;
    __bf16* WhT = (__bf16*)(ws);                      // 8,912,896
    __bf16* WlT = (__bf16*)(ws + 8912896);            // 8,912,896
    __bf16* hh0 = (__bf16*)(ws + 17825792);           // 1,048,576  (zeroed)
    __bf16* hl0 = (__bf16*)(ws + 18874368);           // 1,048,576  (zeroed)
    float*  cb  = (float*)(ws + 19922944);            // 2,097,152  (zeroed)
    __bf16* hh1 = (__bf16*)(ws + 22020096);           // 1,048,576
    __bf16* hl1 = (__bf16*)(ws + 23068672);           // 1,048,576
    __bf16* x0h = (__bf16*)(ws + 24117248);           // 65,536
    __bf16* x0l = (__bf16*)(ws + 24182784);
    __bf16* x1h = (__bf16*)(ws + 24248320);
    __bf16* x1l = (__bf16*)(ws + 24313856);
    __bf16* prh = (__bf16*)(ws + 24379392);
    __bf16* prl = (__bf16*)(ws + 24444928);           // end ~24.5 MB

    wconv<<<dim3(34, 32), 256, 0, stream>>>(Wk, Wr, WhT, WlT);
    init_k<<<1152, 256, 0, stream>>>((uint4*)(ws + 17825792), inputs, x0h, x0l);

    dim3 cgrid(8, 32);
    __bf16 *hch = hh0, *hcl = hl0, *hnh = hh1, *hnl = hl1;

    // warmup over the input window; epilogue converts x_{t+1} for the next step
    for (int t = 0; t < TT; ++t) {
        const __bf16* xh = (t & 1) ? x1h : x0h;
        const __bf16* xl = (t & 1) ? x1l : x0l;
        __bf16* xnh = (t & 1) ? x0h : x1h;
        __bf16* xnl = (t & 1) ? x0l : x1l;
        const float* xnext = (t < TT - 1) ? (inputs + (size_t)(t + 1) * FF) : nullptr;
        lstm_cell_mfma<<<cgrid, 256, 0, stream>>>(xh, xl, hch, hcl, hnh, hnl, cb,
                                                  WhT, WlT, bias, xnext, xnh, xnl);
        __bf16* tp;
        tp = hch; hch = hnh; hnh = tp;
        tp = hcl; hcl = hnl; hnl = tp;
    }

    dense_out<<<BATCH, 256, 0, stream>>>(hch, hcl, Wd, bd, prh, prl, out);

    for (int s = 1; s < OS; ++s) {
        lstm_cell_mfma<<<cgrid, 256, 0, stream>>>(prh, prl, hch, hcl, hnh, hnl, cb,
                                                  WhT, WlT, bias, nullptr, nullptr, nullptr);
        __bf16* tp;
        tp = hch; hch = hnh; hnh = tp;
        tp = hcl; hcl = hnl; hnl = tp;
        dense_out<<<BATCH, 256, 0, stream>>>(hch, hcl, Wd, bd, prh, prl, out + (size_t)s * FF);
    }
}

// Round 3
// 11019.975 us; speedup vs baseline: 1.6292x; 1.1242x over previous
//
#include <hip/hip_runtime.h>
#include <math.h>

#define BATCH 512
#define TT    128
#define FF    64
#define UU    1024
#define ZZ    4096
#define OS    32
#define KTOT  1088
#define NCH   34          // K chunks of 32

typedef __bf16 bf16x8 __attribute__((ext_vector_type(8)));
typedef float f32x4 __attribute__((ext_vector_type(4)));

__device__ __forceinline__ float sigf(float x) { return 1.0f / (1.0f + expf(-x)); }

// async global->LDS, 16B/lane; LDS dest = wave-uniform base + lane*16
__device__ __forceinline__ void async_cp16(void* lds, const void* g) {
    __builtin_amdgcn_global_load_lds(
        (const __attribute__((address_space(1))) void*)g,
        (__attribute__((address_space(3))) void*)lds, 16, 0, 0);
}

// ---------------------------------------------------------------------------
// W precompute: [Wk;Wr] (1088x4096 fp32) -> W^T bf16 hi/lo, gate-interleaved
// n' = 4*u + g, laid out [4096 n'][1088 k]. (Swizzle happens at load time.)
// ---------------------------------------------------------------------------
__global__ __launch_bounds__(256) void wconv(
    const float* __restrict__ Wk, const float* __restrict__ Wr,
    __bf16* __restrict__ WhT, __bf16* __restrict__ WlT)
{
    __shared__ float T[32][129];
    const int k0 = blockIdx.x * 32;   // 34
    const int n0 = blockIdx.y * 128;  // 32
    const int u0 = n0 >> 2;
    const int t = threadIdx.x;
    #pragma unroll
    for (int i = 0; i < 16; ++i) {
        int idx = t + i * 256;
        int u = idx & 31, k = (idx >> 5) & 31, g = idx >> 10;
        int krow = k0 + k;
        int col = g * UU + u0 + u;
        float wv = (krow < FF) ? Wk[(size_t)krow * ZZ + col]
                               : Wr[(size_t)(krow - FF) * ZZ + col];
        T[k][u * 4 + g] = wv;
    }
    __syncthreads();
    #pragma unroll
    for (int i = 0; i < 16; ++i) {
        int idx = t + i * 256;
        int k = idx & 31, np = idx >> 5;
        float wv = T[k][np];
        __bf16 hi = (__bf16)wv;
        size_t o = (size_t)(n0 + np) * KTOT + k0 + k;
        WhT[o] = hi;
        WlT[o] = (__bf16)(wv - (float)hi);
    }
}

// ---------------------------------------------------------------------------
// init: zero h0(hi,lo)+c (4MB contiguous), convert x_0 to bf16 hi/lo
// ---------------------------------------------------------------------------
__global__ __launch_bounds__(256) void init_k(
    uint4* __restrict__ zbase, const float* __restrict__ x0,
    __bf16* __restrict__ xh, __bf16* __restrict__ xl)
{
    const int b = blockIdx.x, t = threadIdx.x;
    if (b < 1024) {
        zbase[(size_t)b * 256 + t] = make_uint4(0u, 0u, 0u, 0u);
    } else {
        int e = (b - 1024) * 256 + t;
        if (e < BATCH * FF) {
            int bb = e >> 6, f = e & 63;
            float v = x0[(size_t)bb * (TT * FF) + f];
            __bf16 hi = (__bf16)v;
            xh[e] = hi;
            xl[e] = (__bf16)(v - (float)hi);
        }
    }
}

// ---------------------------------------------------------------------------
// Fused LSTM cell step. Tile BM=32 x BN=128 (32 units x 4 gates), 4 waves.
// Grid (32 panels, 16 r-tiles) -> XCD = panel%8 (W L2-resident per XCD).
// Double-buffered BK=32 staging, one barrier per chunk, XOR-swizzled slots.
// ---------------------------------------------------------------------------
__global__ __launch_bounds__(256, 2) void lstm_cell_mfma(
    const __bf16* __restrict__ xh, const __bf16* __restrict__ xl,
    const __bf16* __restrict__ hh, const __bf16* __restrict__ hl,
    __bf16* __restrict__ hho, __bf16* __restrict__ hlo_,
    float* __restrict__ c,
    const __bf16* __restrict__ WhT, const __bf16* __restrict__ WlT,
    const float* __restrict__ bias,
    const float* __restrict__ xnext, __bf16* __restrict__ xnh, __bf16* __restrict__ xnl)
{
    // per buffer: ah[32*32] al[32*32] wh[128*32] wl[128*32] = 10240 elems (20KB)
    __shared__ union {
        __bf16 stg[2][10240];
        float z[32 * 132];          // [m][g][u] : m-stride 132, g-stride 33
    } sm;

    const int t = threadIdx.x;
    const int lane = t & 63;
    const int w = t >> 6;
    const int n0 = blockIdx.x * 128;    // panel
    const int r0 = blockIdx.y * 32;     // batch rows
    const int u0 = n0 >> 2;

    const int lr = lane >> 2;           // staging row-in-16
    const int sl = lane & 3;            // staging slot
    const int q  = lane >> 4;
    const int l15 = lane & 15;

    f32x4 acc[2][2];
    #pragma unroll
    for (int i = 0; i < 2; ++i)
        #pragma unroll
        for (int j = 0; j < 2; ++j) acc[i][j] = (f32x4){0.f, 0.f, 0.f, 0.f};

    // ---- staging: one chunk (32 k) into buffer b, XOR-swizzled slots ----
    auto stage = [&](int ch, int b) {
        __bf16* s = sm.stg[b];
        // A: waves 0,1 stage hi; waves 2,3 stage lo (16 rows each)
        {
            int ra = (w & 1) * 16 + lr;                   // local row 0..31
            int swz = (sl ^ ((ra >> 1) & 3)) * 8;
            const __bf16* src = (w < 2) ? ((ch < 2) ? xh : hh)
                                        : ((ch < 2) ? xl : hl);
            size_t go = (ch < 2)
                ? (size_t)(r0 + ra) * FF + ch * 32 + swz
                : (size_t)(r0 + ra) * UU + (ch * 32 - FF) + swz;
            async_cp16(s + ((w < 2) ? 0 : 1024) + (w & 1) * 512, src + go);
        }
        // W: each wave stages 32 rows of hi and lo (2 issues each)
        #pragma unroll
        for (int i = 0; i < 2; ++i) {
            int rw = w * 32 + i * 16 + lr;                // local row 0..127
            int swz = (sl ^ ((rw >> 1) & 3)) * 8;
            size_t go = (size_t)(n0 + rw) * KTOT + ch * 32 + swz;
            async_cp16(s + 2048 + (w * 32 + i * 16) * 32, WhT + go);
            async_cp16(s + 6144 + (w * 32 + i * 16) * 32, WlT + go);
        }
    };

    stage(0, 0);

    #pragma unroll 1
    for (int ch = 0; ch < NCH; ++ch) {
        __syncthreads();                        // buf[ch&1] ready; prev reads done
        if (ch + 1 < NCH) stage(ch + 1, (ch + 1) & 1);

        const __bf16* s = sm.stg[ch & 1];
        bf16x8 afh[2], afl[2], wfh[2], wfl[2];
        #pragma unroll
        for (int mt = 0; mt < 2; ++mt) {
            int ra = mt * 16 + l15;
            int sw = (q ^ ((ra >> 1) & 3)) * 8;
            afh[mt] = *(const bf16x8*)(s + ra * 32 + sw);
            afl[mt] = *(const bf16x8*)(s + 1024 + ra * 32 + sw);
        }
        #pragma unroll
        for (int nt = 0; nt < 2; ++nt) {
            int rw = (w * 2 + nt) * 16 + l15;
            int sw = (q ^ ((rw >> 1) & 3)) * 8;
            wfh[nt] = *(const bf16x8*)(s + 2048 + rw * 32 + sw);
            wfl[nt] = *(const bf16x8*)(s + 6144 + rw * 32 + sw);
        }
        #pragma unroll
        for (int mt = 0; mt < 2; ++mt)
            #pragma unroll
            for (int nt = 0; nt < 2; ++nt) {
                f32x4 a = acc[mt][nt];
                a = __builtin_amdgcn_mfma_f32_16x16x32_bf16(afh[mt], wfh[nt], a, 0, 0, 0);
                a = __builtin_amdgcn_mfma_f32_16x16x32_bf16(afh[mt], wfl[nt], a, 0, 0, 0);
                a = __builtin_amdgcn_mfma_f32_16x16x32_bf16(afl[mt], wfh[nt], a, 0, 0, 0);
                acc[mt][nt] = a;
            }
    }

    __syncthreads();    // all ds_reads done before z aliases the staging union

    // ---- C-frag (col=l15, row=q*4+r) -> z[m][g][u] ----
    #pragma unroll
    for (int mt = 0; mt < 2; ++mt)
        #pragma unroll
        for (int nt = 0; nt < 2; ++nt) {
            int nloc = (w * 2 + nt) * 16 + l15;   // n' local = 4*u + g
            int gs = (nloc & 3) * 33 + (nloc >> 2);
            #pragma unroll
            for (int r = 0; r < 4; ++r) {
                int m = mt * 16 + q * 4 + r;
                sm.z[m * 132 + gs] = acc[mt][nt][r];
            }
        }
    __syncthreads();

    // ---- gates: thread (u = t&31), 4 m-rows each; conflict-free scalar reads ----
    {
        const int ul = t & 31;
        const int uu = u0 + ul;
        const float bi = bias[uu], bfr = bias[UU + uu];
        const float bg = bias[2 * UU + uu], bo = bias[3 * UU + uu];
        #pragma unroll
        for (int rep = 0; rep < 4; ++rep) {
            int m = (t >> 5) * 4 + rep;
            float zi = sm.z[m * 132 + ul];
            float zf = sm.z[m * 132 + 33 + ul];
            float zg = sm.z[m * 132 + 66 + ul];
            float zo = sm.z[m * 132 + 99 + ul];
            size_t idx = (size_t)(r0 + m) * UU + uu;
            float cn = sigf(zf + bfr) * c[idx] + sigf(zi + bi) * tanhf(zg + bg);
            c[idx] = cn;
            float hv = sigf(zo + bo) * tanhf(cn);
            __bf16 hi = (__bf16)hv;
            hho[idx] = hi;
            hlo_[idx] = (__bf16)(hv - (float)hi);
        }
    }

    // ---- convert next warmup x slice (512 blocks x 64 elems = 32768) ----
    if (xnext != nullptr && t < 64) {
        int e = (blockIdx.x + 32 * blockIdx.y) * 64 + t;
        int bb = e >> 6, f = e & 63;
        float v = xnext[(size_t)bb * (TT * FF) + f];
        __bf16 hi = (__bf16)v;
        xnh[e] = hi;
        xnl[e] = (__bf16)(v - (float)hi);
    }
}

// ---------------------------------------------------------------------------
// pred = h @ Wd + bd ; writes fp32 out slice + pred as bf16 hi/lo
// ---------------------------------------------------------------------------
__global__ __launch_bounds__(256) void dense_out(
    const __bf16* __restrict__ hh, const __bf16* __restrict__ hl,
    const float* __restrict__ Wd, const float* __restrict__ bd,
    __bf16* __restrict__ ph, __bf16* __restrict__ pl,
    float* __restrict__ outp)
{
    __shared__ float red[4][64];
    const int t = threadIdx.x, f = t & 63, ks = t >> 6, bb = blockIdx.x;
    const __bf16* hrh = hh + (size_t)bb * UU + ks * 256;
    const __bf16* hrl = hl + (size_t)bb * UU + ks * 256;
    const float* wp = Wd + (size_t)(ks * 256) * FF + f;
    float s = 0.f;
    #pragma unroll 8
    for (int k = 0; k < 256; ++k)
        s += ((float)hrh[k] + (float)hrl[k]) * wp[(size_t)k * FF];
    red[ks][f] = s;
    __syncthreads();
    if (ks == 0) {
        float v = red[0][f] + red[1][f] + red[2][f] + red[3][f] + bd[f];
        outp[(size_t)bb * (OS * FF) + f] = v;
        __bf16 hi = (__bf16)v;
        ph[bb * FF + f] = hi;
        pl[bb * FF + f] = (__bf16)(v - (float)hi);
    }
}

extern "C" void kernel_launch(void* const* d_in, const int* in_sizes, int n_in,
                              void* d_out, int out_size, void* d_ws, size_t ws_size,
                              hipStream_t stream) {
    const float* inputs = (const float*)d_in[0];
    const float* Wk     = (const float*)d_in[1];
    const float* Wr     = (const float*)d_in[2];
    const float* bias   = (const float*)d_in[3];
    const float* Wd     = (const float*)d_in[4];
    const float* bd     = (const float*)d_in[5];
    float* out = (float*)d_out;

    char* ws = (char*)d_ws;
    __bf16* WhT = (__bf16*)(ws);
    __bf16* WlT = (__bf16*)(ws + 8912896);
    __bf16* hh0 = (__bf16*)(ws + 17825792);   // zeroed (4MB block: hh0,hl0,c)
    __bf16* hl0 = (__bf16*)(ws + 18874368);
    float*  cb  = (float*)(ws + 19922944);
    __bf16* hh1 = (__bf16*)(ws + 22020096);
    __bf16* hl1 = (__bf16*)(ws + 23068672);
    __bf16* x0h = (__bf16*)(ws + 24117248);
    __bf16* x0l = (__bf16*)(ws + 24182784);
    __bf16* x1h = (__bf16*)(ws + 24248320);
    __bf16* x1l = (__bf16*)(ws + 24313856);
    __bf16* prh = (__bf16*)(ws + 24379392);
    __bf16* prl = (__bf16*)(ws + 24444928);

    wconv<<<dim3(34, 32), 256, 0, stream>>>(Wk, Wr, WhT, WlT);
    init_k<<<1152, 256, 0, stream>>>((uint4*)(ws + 17825792), inputs, x0h, x0l);

    dim3 cgrid(32, 16);   // (panel, r-tile) -> XCD = panel%8
    __bf16 *hch = hh0, *hcl = hl0, *hnh = hh1, *hnl = hl1;

    for (int t = 0; t < TT; ++t) {
        const __bf16* xh = (t & 1) ? x1h : x0h;
        const __bf16* xl = (t & 1) ? x1l : x0l;
        __bf16* xnh = (t & 1) ? x0h : x1h;
        __bf16* xnl = (t & 1) ? x0l : x1l;
        const float* xnext = (t < TT - 1) ? (inputs + (size_t)(t + 1) * FF) : nullptr;
        lstm_cell_mfma<<<cgrid, 256, 0, stream>>>(xh, xl, hch, hcl, hnh, hnl, cb,
                                                  WhT, WlT, bias, xnext, xnh, xnl);
        __bf16* tp;
        tp = hch; hch = hnh; hnh = tp;
        tp = hcl; hcl = hnl; hnl = tp;
    }

    dense_out<<<BATCH, 256, 0, stream>>>(hch, hcl, Wd, bd, prh, prl, out);

    for (int s = 1; s < OS; ++s) {
        lstm_cell_mfma<<<cgrid, 256, 0, stream>>>(prh, prl, hch, hcl, hnh, hnl, cb,
                                                  WhT, WlT, bias, nullptr, nullptr, nullptr);
        __bf16* tp;
        tp = hch; hch = hnh; hnh = tp;
        tp = hcl; hcl = hnl; hnl = tp;
        dense_out<<<BATCH, 256, 0, stream>>>(hch, hcl, Wd, bd, prh, prl, out + (size_t)s * FF);
    }
}

// Round 4
// 10491.286 us; speedup vs baseline: 1.7113x; 1.0504x over previous
//
#include <hip/hip_runtime.h>
#include <math.h>

#define BATCH 512
#define TT    128
#define FF    64
#define UU    1024
#define ZZ    4096
#define OS    32
#define KTOT  1088

typedef __bf16 bf16x8 __attribute__((ext_vector_type(8)));
typedef float f32x4 __attribute__((ext_vector_type(4)));

__device__ __forceinline__ float sigf(float x) { return 1.0f / (1.0f + expf(-x)); }

// ---------------------------------------------------------------------------
// W precompute: [Wk;Wr] (1088x4096 fp32) -> W^T bf16 hi/lo, gate-interleaved
// n' = 4*u + g, laid out [4096 n'][1088 k].
// ---------------------------------------------------------------------------
__global__ __launch_bounds__(256) void wconv(
    const float* __restrict__ Wk, const float* __restrict__ Wr,
    __bf16* __restrict__ WhT, __bf16* __restrict__ WlT)
{
    __shared__ float T[32][129];
    const int k0 = blockIdx.x * 32;   // 34
    const int n0 = blockIdx.y * 128;  // 32
    const int u0 = n0 >> 2;
    const int t = threadIdx.x;
    #pragma unroll
    for (int i = 0; i < 16; ++i) {
        int idx = t + i * 256;
        int u = idx & 31, k = (idx >> 5) & 31, g = idx >> 10;
        int krow = k0 + k;
        int col = g * UU + u0 + u;
        float wv = (krow < FF) ? Wk[(size_t)krow * ZZ + col]
                               : Wr[(size_t)(krow - FF) * ZZ + col];
        T[k][u * 4 + g] = wv;
    }
    __syncthreads();
    #pragma unroll
    for (int i = 0; i < 16; ++i) {
        int idx = t + i * 256;
        int k = idx & 31, np = idx >> 5;
        float wv = T[k][np];
        __bf16 hi = (__bf16)wv;
        size_t o = (size_t)(n0 + np) * KTOT + k0 + k;
        WhT[o] = hi;
        WlT[o] = (__bf16)(wv - (float)hi);
    }
}

// ---------------------------------------------------------------------------
// init: zero h0(hi,lo)+c (4MB contiguous), convert x_0 to bf16 hi/lo
// ---------------------------------------------------------------------------
__global__ __launch_bounds__(256) void init_k(
    uint4* __restrict__ zbase, const float* __restrict__ x0,
    __bf16* __restrict__ xh, __bf16* __restrict__ xl)
{
    const int b = blockIdx.x, t = threadIdx.x;
    if (b < 1024) {
        zbase[(size_t)b * 256 + t] = make_uint4(0u, 0u, 0u, 0u);
    } else {
        int e = (b - 1024) * 256 + t;
        if (e < BATCH * FF) {
            int bb = e >> 6, f = e & 63;
            float v = x0[(size_t)bb * (TT * FF) + f];
            __bf16 hi = (__bf16)v;
            xh[e] = hi;
            xl[e] = (__bf16)(v - (float)hi);
        }
    }
}

// ---------------------------------------------------------------------------
// Fused LSTM cell step, BARRIER-FREE K-loop.
// Block: 512 thr = 8 waves in 2(mw) x 4(nw); tile BM=64 x BN'=128.
// Wave tile: 2m x 2n 16x16 MFMA tiles, 3-term split-bf16.
// All fragments loaded global->VGPR directly (base ptr + imm offsets);
// redundant reads across waves served by L1. No __syncthreads until epilogue.
// Grid: (32 panels, 8 rtiles) = 256 blocks; XCD = panel%8.
// ---------------------------------------------------------------------------
__global__ __launch_bounds__(512, 2) void lstm_cell_mfma(
    const __bf16* __restrict__ xh, const __bf16* __restrict__ xl,
    const __bf16* __restrict__ hh, const __bf16* __restrict__ hl,
    __bf16* __restrict__ hho, __bf16* __restrict__ hlo_,
    float* __restrict__ c,
    const __bf16* __restrict__ WhT, const __bf16* __restrict__ WlT,
    const float* __restrict__ bias,
    const float* __restrict__ xnext, __bf16* __restrict__ xnh, __bf16* __restrict__ xnl)
{
    __shared__ float z[64 * 132];   // [m][g*33 + u], 33.8 KB

    const int t = threadIdx.x;
    const int lane = t & 63;
    const int w = t >> 6;           // 0..7
    const int mw = w >> 2;          // 0..1
    const int nw = w & 3;           // 0..3
    const int n0 = blockIdx.x * 128;
    const int r0 = blockIdx.y * 64;
    const int u0 = n0 >> 2;
    const int l15 = lane & 15;
    const int q8 = (lane >> 4) * 8;

    f32x4 acc[2][2];
    #pragma unroll
    for (int i = 0; i < 2; ++i)
        #pragma unroll
        for (int j = 0; j < 2; ++j) acc[i][j] = (f32x4){0.f, 0.f, 0.f, 0.f};

    const int arow0 = r0 + mw * 32 + l15;        // m-tile 0 row
    const int arow1 = arow0 + 16;                // m-tile 1 row
    const int wrow0 = n0 + nw * 32 + l15;        // n-tile 0 row
    const int wrow1 = wrow0 + 16;                // n-tile 1 row

    // W base pointers (k=0); per-chunk k offset is an immediate (<4KB)
    const __bf16* pwh0 = WhT + (size_t)wrow0 * KTOT + q8;
    const __bf16* pwh1 = WhT + (size_t)wrow1 * KTOT + q8;
    const __bf16* pwl0 = WlT + (size_t)wrow0 * KTOT + q8;
    const __bf16* pwl1 = WlT + (size_t)wrow1 * KTOT + q8;

    // ---- x chunks (k 0..63) ----
    {
        const __bf16* pxh0 = xh + (size_t)arow0 * FF + q8;
        const __bf16* pxh1 = xh + (size_t)arow1 * FF + q8;
        const __bf16* pxl0 = xl + (size_t)arow0 * FF + q8;
        const __bf16* pxl1 = xl + (size_t)arow1 * FF + q8;
        #pragma unroll
        for (int ch = 0; ch < 2; ++ch) {
            const int k = ch * 32;
            bf16x8 ah0 = *(const bf16x8*)(pxh0 + k);
            bf16x8 ah1 = *(const bf16x8*)(pxh1 + k);
            bf16x8 al0 = *(const bf16x8*)(pxl0 + k);
            bf16x8 al1 = *(const bf16x8*)(pxl1 + k);
            bf16x8 wh0 = *(const bf16x8*)(pwh0 + k);
            bf16x8 wh1 = *(const bf16x8*)(pwh1 + k);
            bf16x8 wl0 = *(const bf16x8*)(pwl0 + k);
            bf16x8 wl1 = *(const bf16x8*)(pwl1 + k);
            acc[0][0] = __builtin_amdgcn_mfma_f32_16x16x32_bf16(ah0, wh0, acc[0][0], 0, 0, 0);
            acc[0][0] = __builtin_amdgcn_mfma_f32_16x16x32_bf16(ah0, wl0, acc[0][0], 0, 0, 0);
            acc[0][0] = __builtin_amdgcn_mfma_f32_16x16x32_bf16(al0, wh0, acc[0][0], 0, 0, 0);
            acc[0][1] = __builtin_amdgcn_mfma_f32_16x16x32_bf16(ah0, wh1, acc[0][1], 0, 0, 0);
            acc[0][1] = __builtin_amdgcn_mfma_f32_16x16x32_bf16(ah0, wl1, acc[0][1], 0, 0, 0);
            acc[0][1] = __builtin_amdgcn_mfma_f32_16x16x32_bf16(al0, wh1, acc[0][1], 0, 0, 0);
            acc[1][0] = __builtin_amdgcn_mfma_f32_16x16x32_bf16(ah1, wh0, acc[1][0], 0, 0, 0);
            acc[1][0] = __builtin_amdgcn_mfma_f32_16x16x32_bf16(ah1, wl0, acc[1][0], 0, 0, 0);
            acc[1][0] = __builtin_amdgcn_mfma_f32_16x16x32_bf16(al1, wh0, acc[1][0], 0, 0, 0);
            acc[1][1] = __builtin_amdgcn_mfma_f32_16x16x32_bf16(ah1, wh1, acc[1][1], 0, 0, 0);
            acc[1][1] = __builtin_amdgcn_mfma_f32_16x16x32_bf16(ah1, wl1, acc[1][1], 0, 0, 0);
            acc[1][1] = __builtin_amdgcn_mfma_f32_16x16x32_bf16(al1, wh1, acc[1][1], 0, 0, 0);
        }
    }

    // ---- h chunks (k 64..1087), W k-offset = 64 + 32*ch ----
    {
        const __bf16* pah0 = hh + (size_t)arow0 * UU + q8;
        const __bf16* pah1 = hh + (size_t)arow1 * UU + q8;
        const __bf16* pal0 = hl + (size_t)arow0 * UU + q8;
        const __bf16* pal1 = hl + (size_t)arow1 * UU + q8;
        #pragma unroll
        for (int ch = 0; ch < 32; ++ch) {
            const int k = ch * 32;         // h-k offset (bytes 0..1984*2, imm ok)
            const int kw = 64 + ch * 32;   // W-k offset
            bf16x8 ah0 = *(const bf16x8*)(pah0 + k);
            bf16x8 ah1 = *(const bf16x8*)(pah1 + k);
            bf16x8 al0 = *(const bf16x8*)(pal0 + k);
            bf16x8 al1 = *(const bf16x8*)(pal1 + k);
            bf16x8 wh0 = *(const bf16x8*)(pwh0 + kw);
            bf16x8 wh1 = *(const bf16x8*)(pwh1 + kw);
            bf16x8 wl0 = *(const bf16x8*)(pwl0 + kw);
            bf16x8 wl1 = *(const bf16x8*)(pwl1 + kw);
            acc[0][0] = __builtin_amdgcn_mfma_f32_16x16x32_bf16(ah0, wh0, acc[0][0], 0, 0, 0);
            acc[0][0] = __builtin_amdgcn_mfma_f32_16x16x32_bf16(ah0, wl0, acc[0][0], 0, 0, 0);
            acc[0][0] = __builtin_amdgcn_mfma_f32_16x16x32_bf16(al0, wh0, acc[0][0], 0, 0, 0);
            acc[0][1] = __builtin_amdgcn_mfma_f32_16x16x32_bf16(ah0, wh1, acc[0][1], 0, 0, 0);
            acc[0][1] = __builtin_amdgcn_mfma_f32_16x16x32_bf16(ah0, wl1, acc[0][1], 0, 0, 0);
            acc[0][1] = __builtin_amdgcn_mfma_f32_16x16x32_bf16(al0, wh1, acc[0][1], 0, 0, 0);
            acc[1][0] = __builtin_amdgcn_mfma_f32_16x16x32_bf16(ah1, wh0, acc[1][0], 0, 0, 0);
            acc[1][0] = __builtin_amdgcn_mfma_f32_16x16x32_bf16(ah1, wl0, acc[1][0], 0, 0, 0);
            acc[1][0] = __builtin_amdgcn_mfma_f32_16x16x32_bf16(al1, wh0, acc[1][0], 0, 0, 0);
            acc[1][1] = __builtin_amdgcn_mfma_f32_16x16x32_bf16(ah1, wh1, acc[1][1], 0, 0, 0);
            acc[1][1] = __builtin_amdgcn_mfma_f32_16x16x32_bf16(ah1, wl1, acc[1][1], 0, 0, 0);
            acc[1][1] = __builtin_amdgcn_mfma_f32_16x16x32_bf16(al1, wh1, acc[1][1], 0, 0, 0);
        }
    }

    // ---- epilogue: C-frag (col=l15, row=q*4+r) -> z[m][g][u] ----
    {
        const int q = lane >> 4;
        #pragma unroll
        for (int mt = 0; mt < 2; ++mt)
            #pragma unroll
            for (int nt = 0; nt < 2; ++nt) {
                int nloc = nw * 32 + nt * 16 + l15;      // n' local = 4u+g
                int gs = (nloc & 3) * 33 + (nloc >> 2);
                #pragma unroll
                for (int r = 0; r < 4; ++r) {
                    int m = mw * 32 + mt * 16 + q * 4 + r;
                    z[m * 132 + gs] = acc[mt][nt][r];
                }
            }
    }
    __syncthreads();

    // ---- gates: thread (u = t&31), 4 m-rows each ----
    {
        const int ul = t & 31;
        const int uu = u0 + ul;
        const float bi = bias[uu], bfr = bias[UU + uu];
        const float bg = bias[2 * UU + uu], bo = bias[3 * UU + uu];
        #pragma unroll
        for (int rep = 0; rep < 4; ++rep) {
            int m = (t >> 5) * 4 + rep;
            float zi = z[m * 132 + ul];
            float zf = z[m * 132 + 33 + ul];
            float zg = z[m * 132 + 66 + ul];
            float zo = z[m * 132 + 99 + ul];
            size_t idx = (size_t)(r0 + m) * UU + uu;
            float cn = sigf(zf + bfr) * c[idx] + sigf(zi + bi) * tanhf(zg + bg);
            c[idx] = cn;
            float hv = sigf(zo + bo) * tanhf(cn);
            __bf16 hi = (__bf16)hv;
            hho[idx] = hi;
            hlo_[idx] = (__bf16)(hv - (float)hi);
        }
    }

    // ---- convert next warmup x slice (256 blocks x 128 elems = 32768) ----
    if (xnext != nullptr && t < 128) {
        int e = (blockIdx.x + 32 * blockIdx.y) * 128 + t;
        int bb = e >> 6, f = e & 63;
        float v = xnext[(size_t)bb * (TT * FF) + f];
        __bf16 hi = (__bf16)v;
        xnh[e] = hi;
        xnl[e] = (__bf16)(v - (float)hi);
    }
}

// ---------------------------------------------------------------------------
// pred = h @ Wd + bd ; writes fp32 out slice + pred as bf16 hi/lo
// ---------------------------------------------------------------------------
__global__ __launch_bounds__(256) void dense_out(
    const __bf16* __restrict__ hh, const __bf16* __restrict__ hl,
    const float* __restrict__ Wd, const float* __restrict__ bd,
    __bf16* __restrict__ ph, __bf16* __restrict__ pl,
    float* __restrict__ outp)
{
    __shared__ float red[4][64];
    const int t = threadIdx.x, f = t & 63, ks = t >> 6, bb = blockIdx.x;
    const bf16x8* hrh = (const bf16x8*)(hh + (size_t)bb * UU + ks * 256);
    const bf16x8* hrl = (const bf16x8*)(hl + (size_t)bb * UU + ks * 256);
    const float* wp = Wd + (size_t)(ks * 256) * FF + f;
    float s = 0.f;
    #pragma unroll 4
    for (int v = 0; v < 32; ++v) {
        bf16x8 a = hrh[v], b = hrl[v];
        #pragma unroll
        for (int j = 0; j < 8; ++j)
            s += ((float)a[j] + (float)b[j]) * wp[(size_t)(v * 8 + j) * FF];
    }
    red[ks][f] = s;
    __syncthreads();
    if (ks == 0) {
        float vv = red[0][f] + red[1][f] + red[2][f] + red[3][f] + bd[f];
        outp[(size_t)bb * (OS * FF) + f] = vv;
        __bf16 hi = (__bf16)vv;
        ph[bb * FF + f] = hi;
        pl[bb * FF + f] = (__bf16)(vv - (float)hi);
    }
}

extern "C" void kernel_launch(void* const* d_in, const int* in_sizes, int n_in,
                              void* d_out, int out_size, void* d_ws, size_t ws_size,
                              hipStream_t stream) {
    const float* inputs = (const float*)d_in[0];
    const float* Wk     = (const float*)d_in[1];
    const float* Wr     = (const float*)d_in[2];
    const float* bias   = (const float*)d_in[3];
    const float* Wd     = (const float*)d_in[4];
    const float* bd     = (const float*)d_in[5];
    float* out = (float*)d_out;

    char* ws = (char*)d_ws;
    __bf16* WhT = (__bf16*)(ws);
    __bf16* WlT = (__bf16*)(ws + 8912896);
    __bf16* hh0 = (__bf16*)(ws + 17825792);   // zeroed (4MB block: hh0,hl0,c)
    __bf16* hl0 = (__bf16*)(ws + 18874368);
    float*  cb  = (float*)(ws + 19922944);
    __bf16* hh1 = (__bf16*)(ws + 22020096);
    __bf16* hl1 = (__bf16*)(ws + 23068672);
    __bf16* x0h = (__bf16*)(ws + 24117248);
    __bf16* x0l = (__bf16*)(ws + 24182784);
    __bf16* x1h = (__bf16*)(ws + 24248320);
    __bf16* x1l = (__bf16*)(ws + 24313856);
    __bf16* prh = (__bf16*)(ws + 24379392);
    __bf16* prl = (__bf16*)(ws + 24444928);

    wconv<<<dim3(34, 32), 256, 0, stream>>>(Wk, Wr, WhT, WlT);
    init_k<<<1152, 256, 0, stream>>>((uint4*)(ws + 17825792), inputs, x0h, x0l);

    dim3 cgrid(32, 8);   // (panel, rtile) -> XCD = panel%8
    __bf16 *hch = hh0, *hcl = hl0, *hnh = hh1, *hnl = hl1;

    for (int t = 0; t < TT; ++t) {
        const __bf16* xh = (t & 1) ? x1h : x0h;
        const __bf16* xl = (t & 1) ? x1l : x0l;
        __bf16* xnh = (t & 1) ? x0h : x1h;
        __bf16* xnl = (t & 1) ? x0l : x1l;
        const float* xnext = (t < TT - 1) ? (inputs + (size_t)(t + 1) * FF) : nullptr;
        lstm_cell_mfma<<<cgrid, 512, 0, stream>>>(xh, xl, hch, hcl, hnh, hnl, cb,
                                                  WhT, WlT, bias, xnext, xnh, xnl);
        __bf16* tp;
        tp = hch; hch = hnh; hnh = tp;
        tp = hcl; hcl = hnl; hnl = tp;
    }

    dense_out<<<BATCH, 256, 0, stream>>>(hch, hcl, Wd, bd, prh, prl, out);

    for (int s = 1; s < OS; ++s) {
        lstm_cell_mfma<<<cgrid, 512, 0, stream>>>(prh, prl, hch, hcl, hnh, hnl, cb,
                                                  WhT, WlT, bias, nullptr, nullptr, nullptr);
        __bf16* tp;
        tp = hch; hch = hnh; hnh = tp;
        tp = hcl; hcl = hnl; hnl = tp;
        dense_out<<<BATCH, 256, 0, stream>>>(hch, hcl, Wd, bd, prh, prl, out + (size_t)s * FF);
    }
}

// Round 5
// 5776.007 us; speedup vs baseline: 3.1084x; 1.8164x over previous
//
#include <hip/hip_runtime.h>
#include <math.h>

#define BATCH 512
#define TT    128
#define FF    64
#define UU    1024
#define ZZ    4096
#define OS    32
#define KTOT  1088
#define NCH   34          // K chunks of 32

typedef _Float16 f16x8 __attribute__((ext_vector_type(8)));
typedef float f32x16 __attribute__((ext_vector_type(16)));

__device__ __forceinline__ float sigf(float x) { return 1.0f / (1.0f + expf(-x)); }

// ---------------------------------------------------------------------------
// W precompute: [Wk;Wr] (1088x4096 fp32) -> W^T f16, gate-interleaved
// n' = 4*u + g, laid out [4096 n'][1088 k].
// ---------------------------------------------------------------------------
__global__ __launch_bounds__(256) void wconv(
    const float* __restrict__ Wk, const float* __restrict__ Wr,
    _Float16* __restrict__ WT)
{
    __shared__ float T[32][129];
    const int k0 = blockIdx.x * 32;   // 34
    const int n0 = blockIdx.y * 128;  // 32
    const int u0 = n0 >> 2;
    const int t = threadIdx.x;
    #pragma unroll
    for (int i = 0; i < 16; ++i) {
        int idx = t + i * 256;
        int u = idx & 31, k = (idx >> 5) & 31, g = idx >> 10;
        int krow = k0 + k;
        int col = g * UU + u0 + u;
        float wv = (krow < FF) ? Wk[(size_t)krow * ZZ + col]
                               : Wr[(size_t)(krow - FF) * ZZ + col];
        T[k][u * 4 + g] = wv;
    }
    __syncthreads();
    #pragma unroll
    for (int i = 0; i < 16; ++i) {
        int idx = t + i * 256;
        int k = idx & 31, np = idx >> 5;
        WT[(size_t)(n0 + np) * KTOT + k0 + k] = (_Float16)T[k][np];
    }
}

// ---------------------------------------------------------------------------
// init: zero hF0 + c (3MB contiguous), convert x_0 to f16
// grid: 768 zero blocks + 128 conversion blocks = 896
// ---------------------------------------------------------------------------
__global__ __launch_bounds__(256) void init_k(
    uint4* __restrict__ zbase, const float* __restrict__ x0,
    _Float16* __restrict__ xF)
{
    const int b = blockIdx.x, t = threadIdx.x;
    if (b < 768) {
        zbase[(size_t)b * 256 + t] = make_uint4(0u, 0u, 0u, 0u);
    } else {
        int e = (b - 768) * 256 + t;   // 0..32767
        int bb = e >> 6, f = e & 63;
        xF[e] = (_Float16)x0[(size_t)bb * (TT * FF) + f];
    }
}

// ---------------------------------------------------------------------------
// Fused LSTM cell step: f16 single-term GEMM on 32x32x16 MFMA,
// explicit depth-4 software pipeline, no K-loop barriers.
// Block: 512 thr = 8 waves (mw 0..1 x nw 0..3); tile BM=64 x BN'=128.
// Wave tile: one 32x32 MFMA tile. Grid (32 panels, 8 rtiles); XCD = panel%8.
// ---------------------------------------------------------------------------
__global__ __launch_bounds__(512, 2) void lstm_cell_mfma(
    const _Float16* __restrict__ xF,      // [512][64]
    const _Float16* __restrict__ hF,      // [512][1024]
    _Float16* __restrict__ hFo,           // [512][1024]
    float* __restrict__ c,                // [512][1024] in-place
    const _Float16* __restrict__ WT,      // [4096 n'][1088 k]
    const float* __restrict__ bias,       // [4096] natural order
    const float* __restrict__ xnext, _Float16* __restrict__ xnF)
{
    __shared__ float z[64 * 132];   // [m][g*33 + u], 33.8 KB

    const int t = threadIdx.x;
    const int lane = t & 63;
    const int w  = t >> 6;
    const int mw = w >> 2;          // 0..1
    const int nw = w & 3;           // 0..3
    const int n0 = blockIdx.x * 128;
    const int r0 = blockIdx.y * 64;
    const int u0 = n0 >> 2;
    const int l31 = lane & 31;
    const int kb = (lane >> 5) * 8; // k-half offset within 16

    const int arow = r0 + mw * 32 + l31;
    const int wrow = n0 + nw * 32 + l31;

    const _Float16* pAx = xF + (size_t)arow * FF + kb;
    const _Float16* pAh = hF + (size_t)arow * UU + kb;
    const _Float16* pW  = WT + (size_t)wrow * KTOT + kb;

    f32x16 acc;
    #pragma unroll
    for (int i = 0; i < 16; ++i) acc[i] = 0.f;

    f16x8 af[4][2], wf[4][2];       // [stage&3][k16 half]

    // stage loader: chunk ch covers k in [ch*32, ch*32+32)
#define LOADSTAGE(ch)                                                        \
    {                                                                        \
        const int _s = (ch) & 3;                                             \
        _Pragma("unroll")                                                    \
        for (int hf = 0; hf < 2; ++hf) {                                     \
            const int k = (ch) * 32 + hf * 16;                               \
            af[_s][hf] = ((ch) < 2) ? *(const f16x8*)(pAx + k)               \
                                    : *(const f16x8*)(pAh + (k - FF));       \
            wf[_s][hf] = *(const f16x8*)(pW + k);                            \
        }                                                                    \
    }

    LOADSTAGE(0)
    LOADSTAGE(1)
    LOADSTAGE(2)

    #pragma unroll
    for (int ch = 0; ch < NCH; ++ch) {
        if (ch + 3 < NCH) LOADSTAGE(ch + 3)
        const int s = ch & 3;
        acc = __builtin_amdgcn_mfma_f32_32x32x16_f16(af[s][0], wf[s][0], acc, 0, 0, 0);
        acc = __builtin_amdgcn_mfma_f32_32x32x16_f16(af[s][1], wf[s][1], acc, 0, 0, 0);
    }
#undef LOADSTAGE

    // ---- C-frag (32x32: col=lane&31, row=(r&3)+8*(r>>2)+4*(lane>>5)) -> z ----
    {
        const int nloc = nw * 32 + l31;             // n' local = 4u+g
        const int gs = (nloc & 3) * 33 + (nloc >> 2);
        const int rbase = mw * 32 + 4 * (lane >> 5);
        #pragma unroll
        for (int r = 0; r < 16; ++r) {
            int m = rbase + (r & 3) + 8 * (r >> 2);
            z[m * 132 + gs] = acc[r];
        }
    }
    __syncthreads();

    // ---- gates: thread (u = t&31), 4 m-rows each ----
    {
        const int ul = t & 31;
        const int uu = u0 + ul;
        const float bi = bias[uu], bfr = bias[UU + uu];
        const float bg = bias[2 * UU + uu], bo = bias[3 * UU + uu];
        #pragma unroll
        for (int rep = 0; rep < 4; ++rep) {
            int m = (t >> 5) * 4 + rep;
            float zi = z[m * 132 + ul];
            float zf = z[m * 132 + 33 + ul];
            float zg = z[m * 132 + 66 + ul];
            float zo = z[m * 132 + 99 + ul];
            size_t idx = (size_t)(r0 + m) * UU + uu;
            float cn = sigf(zf + bfr) * c[idx] + sigf(zi + bi) * tanhf(zg + bg);
            c[idx] = cn;
            hFo[idx] = (_Float16)(sigf(zo + bo) * tanhf(cn));
        }
    }

    // ---- convert next warmup x slice (256 blocks x 128 = 32768 elems) ----
    if (xnext != nullptr && t < 128) {
        int e = (blockIdx.x + 32 * blockIdx.y) * 128 + t;
        int bb = e >> 6, f = e & 63;
        xnF[e] = (_Float16)xnext[(size_t)bb * (TT * FF) + f];
    }
}

// ---------------------------------------------------------------------------
// pred = h @ Wd + bd ; writes fp32 out slice + pred as f16
// ---------------------------------------------------------------------------
__global__ __launch_bounds__(256) void dense_out(
    const _Float16* __restrict__ hF,
    const float* __restrict__ Wd, const float* __restrict__ bd,
    _Float16* __restrict__ pF, float* __restrict__ outp)
{
    __shared__ float red[4][64];
    const int t = threadIdx.x, f = t & 63, ks = t >> 6, bb = blockIdx.x;
    const f16x8* hr = (const f16x8*)(hF + (size_t)bb * UU + ks * 256);
    const float* wp = Wd + (size_t)(ks * 256) * FF + f;
    float s = 0.f;
    #pragma unroll 4
    for (int v = 0; v < 32; ++v) {
        f16x8 a = hr[v];
        #pragma unroll
        for (int j = 0; j < 8; ++j)
            s += (float)a[j] * wp[(size_t)(v * 8 + j) * FF];
    }
    red[ks][f] = s;
    __syncthreads();
    if (ks == 0) {
        float vv = red[0][f] + red[1][f] + red[2][f] + red[3][f] + bd[f];
        outp[(size_t)bb * (OS * FF) + f] = vv;
        pF[bb * FF + f] = (_Float16)vv;
    }
}

extern "C" void kernel_launch(void* const* d_in, const int* in_sizes, int n_in,
                              void* d_out, int out_size, void* d_ws, size_t ws_size,
                              hipStream_t stream) {
    const float* inputs = (const float*)d_in[0];
    const float* Wk     = (const float*)d_in[1];
    const float* Wr     = (const float*)d_in[2];
    const float* bias   = (const float*)d_in[3];
    const float* Wd     = (const float*)d_in[4];
    const float* bd     = (const float*)d_in[5];
    float* out = (float*)d_out;

    char* ws = (char*)d_ws;
    _Float16* hF0 = (_Float16*)(ws);                  // 1 MB   (zeroed)
    float*    cb  = (float*)(ws + 1048576);           // 2 MB   (zeroed)
    _Float16* hF1 = (_Float16*)(ws + 3145728);        // 1 MB
    _Float16* WT  = (_Float16*)(ws + 4194304);        // 8.9 MB
    _Float16* x0F = (_Float16*)(ws + 13107200);       // 64 KB
    _Float16* x1F = (_Float16*)(ws + 13172736);       // 64 KB
    _Float16* prF = (_Float16*)(ws + 13238272);       // 64 KB

    wconv<<<dim3(34, 32), 256, 0, stream>>>(Wk, Wr, WT);
    init_k<<<896, 256, 0, stream>>>((uint4*)ws, inputs, x0F);

    dim3 cgrid(32, 8);   // (panel, rtile) -> XCD = panel%8
    _Float16 *hc = hF0, *hn = hF1;

    for (int t = 0; t < TT; ++t) {
        const _Float16* xF = (t & 1) ? x1F : x0F;
        _Float16* xnF = (t & 1) ? x0F : x1F;
        const float* xnext = (t < TT - 1) ? (inputs + (size_t)(t + 1) * FF) : nullptr;
        lstm_cell_mfma<<<cgrid, 512, 0, stream>>>(xF, hc, hn, cb, WT, bias, xnext, xnF);
        _Float16* tp = hc; hc = hn; hn = tp;
    }

    dense_out<<<BATCH, 256, 0, stream>>>(hc, Wd, bd, prF, out);

    for (int s = 1; s < OS; ++s) {
        lstm_cell_mfma<<<cgrid, 512, 0, stream>>>(prF, hc, hn, cb, WT, bias, nullptr, nullptr);
        _Float16* tp = hc; hc = hn; hn = tp;
        dense_out<<<BATCH, 256, 0, stream>>>(hc, Wd, bd, prF, out + (size_t)s * FF);
    }
}

// Round 6
// 2756.903 us; speedup vs baseline: 6.5123x; 2.0951x over previous
//
#include <hip/hip_runtime.h>
#include <math.h>

#define BATCH 512
#define TT    128
#define FF    64
#define UU    1024
#define ZZ    4096
#define OS    32
#define KTOT  1088
#define NCH   17            // K chunks of 64
#define CROW  72            // LDS row stride in f16 elems (64 + 8 pad = 144 B)
#define ABASE 0             // A region: 64 rows
#define WBASE (64 * CROW)   // W region: 128 rows
#define CBUF  (192 * CROW)  // 13824 elems = 27648 B per chunk buffer

typedef _Float16 f16x8 __attribute__((ext_vector_type(8)));
typedef float f32x16 __attribute__((ext_vector_type(16)));

__device__ __forceinline__ float sigf(float x) { return 1.0f / (1.0f + expf(-x)); }

// ---------------------------------------------------------------------------
// W precompute: [Wk;Wr] (1088x4096 fp32) -> W^T f16, gate-interleaved
// n' = 4*u + g, laid out [4096 n'][1088 k].
// ---------------------------------------------------------------------------
__global__ __launch_bounds__(256) void wconv(
    const float* __restrict__ Wk, const float* __restrict__ Wr,
    _Float16* __restrict__ WT)
{
    __shared__ float T[32][129];
    const int k0 = blockIdx.x * 32;   // 34
    const int n0 = blockIdx.y * 128;  // 32
    const int u0 = n0 >> 2;
    const int t = threadIdx.x;
    #pragma unroll
    for (int i = 0; i < 16; ++i) {
        int idx = t + i * 256;
        int u = idx & 31, k = (idx >> 5) & 31, g = idx >> 10;
        int krow = k0 + k;
        int col = g * UU + u0 + u;
        float wv = (krow < FF) ? Wk[(size_t)krow * ZZ + col]
                               : Wr[(size_t)(krow - FF) * ZZ + col];
        T[k][u * 4 + g] = wv;
    }
    __syncthreads();
    #pragma unroll
    for (int i = 0; i < 16; ++i) {
        int idx = t + i * 256;
        int k = idx & 31, np = idx >> 5;
        WT[(size_t)(n0 + np) * KTOT + k0 + k] = (_Float16)T[k][np];
    }
}

// ---------------------------------------------------------------------------
// init: zero hF0 + c (3MB contiguous), convert x_0 to f16
// ---------------------------------------------------------------------------
__global__ __launch_bounds__(256) void init_k(
    uint4* __restrict__ zbase, const float* __restrict__ x0,
    _Float16* __restrict__ xF)
{
    const int b = blockIdx.x, t = threadIdx.x;
    if (b < 768) {
        zbase[(size_t)b * 256 + t] = make_uint4(0u, 0u, 0u, 0u);
    } else {
        int e = (b - 768) * 256 + t;   // 0..32767
        int bb = e >> 6, f = e & 63;
        xF[e] = (_Float16)x0[(size_t)bb * (TT * FF) + f];
    }
}

// ---------------------------------------------------------------------------
// Fused LSTM cell step: f16 GEMM on 32x32x16 MFMA.
// Register-staged LDS double-buffer, RAW s_barrier + manual lgkmcnt(0)
// (no vmcnt(0) drain): chunk ch+2 loads in flight across the barrier.
// Block: 512 thr = 8 waves (mw 0..1 x nw 0..3); tile BM=64 x BN'=128, BK=64.
// Grid (32 panels, 8 rtiles); XCD = panel%8.
// ---------------------------------------------------------------------------
__global__ __launch_bounds__(512, 2) void lstm_cell_mfma(
    const _Float16* __restrict__ xF,      // [512][64]
    const _Float16* __restrict__ hF,      // [512][1024]
    _Float16* __restrict__ hFo,           // [512][1024]
    float* __restrict__ c,                // [512][1024] in-place
    const _Float16* __restrict__ WT,      // [4096 n'][1088 k]
    const float* __restrict__ bias,       // [4096] natural order
    const float* __restrict__ xnext, _Float16* __restrict__ xnF)
{
    __shared__ __align__(16) char smem[2 * CBUF * 2];   // 55296 B (2 chunk buffers)
    _Float16* lds = (_Float16*)smem;
    float* z = (float*)smem;                            // epilogue overlay [m][g*33+u]

    const int t = threadIdx.x;
    const int lane = t & 63;
    const int w  = t >> 6;
    const int mw = w >> 2;          // 0..1
    const int nw = w & 3;           // 0..3
    const int n0 = blockIdx.x * 128;
    const int r0 = blockIdx.y * 64;
    const int u0 = n0 >> 2;
    const int l31 = lane & 31;

    // ---- staging: thread t owns A row t>>3 seg t&7 (16B) + two W 16B slots ----
    const int srow = t >> 3;        // 0..63
    const int sseg = t & 7;         // 0..7
    const _Float16* aAx = xF + (size_t)(r0 + srow) * FF + sseg * 8;
    const _Float16* aAh = hF + (size_t)(r0 + srow) * UU + sseg * 8;
    const _Float16* aW0 = WT + (size_t)(n0 + srow) * KTOT + sseg * 8;        // W rows 0..63
    const _Float16* aW1 = WT + (size_t)(n0 + 64 + srow) * KTOT + sseg * 8;   // W rows 64..127
    const int wA  = ABASE + srow * CROW + sseg * 8;
    const int wW0 = WBASE + srow * CROW + sseg * 8;
    const int wW1 = WBASE + (64 + srow) * CROW + sseg * 8;

    uint4 sA[2], sW0[2], sW1[2];    // chunk c lives in slot c&1

    // ---- fragment read offsets ----
    const int fra = (mw * 32 + l31) * CROW + (lane >> 5) * 8;           // A row
    const int frw = WBASE + (nw * 32 + l31) * CROW + (lane >> 5) * 8;   // W row

    f32x16 acc;
    #pragma unroll
    for (int i = 0; i < 16; ++i) acc[i] = 0.f;

#define LOADC(ch)                                                              \
    {                                                                          \
        const int _s = (ch) & 1;                                               \
        sA[_s]  = ((ch) == 0) ? *(const uint4*)aAx                             \
                              : *(const uint4*)(aAh + ((ch) - 1) * 64);        \
        sW0[_s] = *(const uint4*)(aW0 + (ch) * 64);                            \
        sW1[_s] = *(const uint4*)(aW1 + (ch) * 64);                            \
    }
#define WRITEC(ch)                                                             \
    {                                                                          \
        const int _s = (ch) & 1;                                               \
        _Float16* _b = lds + _s * CBUF;                                        \
        *(uint4*)(_b + wA)  = sA[_s];                                          \
        *(uint4*)(_b + wW0) = sW0[_s];                                         \
        *(uint4*)(_b + wW1) = sW1[_s];                                         \
    }

    LOADC(0)
    LOADC(1)
    WRITEC(0)

    #pragma unroll
    for (int ch = 0; ch < NCH; ++ch) {
        if (ch + 2 < NCH) LOADC(ch + 2)
        // lgkmcnt(0) only: own ds ops drained; vm loads stay in flight.
        __builtin_amdgcn_s_waitcnt(0xC07F);
        __builtin_amdgcn_s_barrier();
        if (ch + 1 < NCH) WRITEC(ch + 1)        // compiler waits vmcnt for these regs only
        const _Float16* b = lds + (ch & 1) * CBUF;
        #pragma unroll
        for (int s = 0; s < 4; ++s) {
            f16x8 af = *(const f16x8*)(b + fra + s * 16);
            f16x8 wf = *(const f16x8*)(b + frw + s * 16);
            acc = __builtin_amdgcn_mfma_f32_32x32x16_f16(af, wf, acc, 0, 0, 0);
        }
    }
#undef LOADC
#undef WRITEC

    __syncthreads();   // full drain before z overlays the staging buffers

    // ---- C-frag (32x32: col=lane&31, row=(r&3)+8*(r>>2)+4*(lane>>5)) -> z ----
    {
        const int nloc = nw * 32 + l31;             // n' local = 4u+g
        const int gs = (nloc & 3) * 33 + (nloc >> 2);
        const int rbase = mw * 32 + 4 * (lane >> 5);
        #pragma unroll
        for (int r = 0; r < 16; ++r) {
            int m = rbase + (r & 3) + 8 * (r >> 2);
            z[m * 132 + gs] = acc[r];
        }
    }
    __syncthreads();

    // ---- gates: thread (u = t&31), 4 m-rows each ----
    {
        const int ul = t & 31;
        const int uu = u0 + ul;
        const float bi = bias[uu], bfr = bias[UU + uu];
        const float bg = bias[2 * UU + uu], bo = bias[3 * UU + uu];
        #pragma unroll
        for (int rep = 0; rep < 4; ++rep) {
            int m = (t >> 5) * 4 + rep;
            float zi = z[m * 132 + ul];
            float zf = z[m * 132 + 33 + ul];
            float zg = z[m * 132 + 66 + ul];
            float zo = z[m * 132 + 99 + ul];
            size_t idx = (size_t)(r0 + m) * UU + uu;
            float cn = sigf(zf + bfr) * c[idx] + sigf(zi + bi) * tanhf(zg + bg);
            c[idx] = cn;
            hFo[idx] = (_Float16)(sigf(zo + bo) * tanhf(cn));
        }
    }

    // ---- convert next warmup x slice (256 blocks x 128 = 32768 elems) ----
    if (xnext != nullptr && t < 128) {
        int e = (blockIdx.x + 32 * blockIdx.y) * 128 + t;
        int bb = e >> 6, f = e & 63;
        xnF[e] = (_Float16)xnext[(size_t)bb * (TT * FF) + f];
    }
}

// ---------------------------------------------------------------------------
// pred = h @ Wd + bd ; writes fp32 out slice + pred as f16
// ---------------------------------------------------------------------------
__global__ __launch_bounds__(256) void dense_out(
    const _Float16* __restrict__ hF,
    const float* __restrict__ Wd, const float* __restrict__ bd,
    _Float16* __restrict__ pF, float* __restrict__ outp)
{
    __shared__ float red[4][64];
    const int t = threadIdx.x, f = t & 63, ks = t >> 6, bb = blockIdx.x;
    const f16x8* hr = (const f16x8*)(hF + (size_t)bb * UU + ks * 256);
    const float* wp = Wd + (size_t)(ks * 256) * FF + f;
    float s = 0.f;
    #pragma unroll 4
    for (int v = 0; v < 32; ++v) {
        f16x8 a = hr[v];
        #pragma unroll
        for (int j = 0; j < 8; ++j)
            s += (float)a[j] * wp[(size_t)(v * 8 + j) * FF];
    }
    red[ks][f] = s;
    __syncthreads();
    if (ks == 0) {
        float vv = red[0][f] + red[1][f] + red[2][f] + red[3][f] + bd[f];
        outp[(size_t)bb * (OS * FF) + f] = vv;
        pF[bb * FF + f] = (_Float16)vv;
    }
}

extern "C" void kernel_launch(void* const* d_in, const int* in_sizes, int n_in,
                              void* d_out, int out_size, void* d_ws, size_t ws_size,
                              hipStream_t stream) {
    const float* inputs = (const float*)d_in[0];
    const float* Wk     = (const float*)d_in[1];
    const float* Wr     = (const float*)d_in[2];
    const float* bias   = (const float*)d_in[3];
    const float* Wd     = (const float*)d_in[4];
    const float* bd     = (const float*)d_in[5];
    float* out = (float*)d_out;

    char* ws = (char*)d_ws;
    _Float16* hF0 = (_Float16*)(ws);                  // 1 MB   (zeroed)
    float*    cb  = (float*)(ws + 1048576);           // 2 MB   (zeroed)
    _Float16* hF1 = (_Float16*)(ws + 3145728);        // 1 MB
    _Float16* WT  = (_Float16*)(ws + 4194304);        // 8.9 MB
    _Float16* x0F = (_Float16*)(ws + 13107200);       // 64 KB
    _Float16* x1F = (_Float16*)(ws + 13172736);       // 64 KB
    _Float16* prF = (_Float16*)(ws + 13238272);       // 64 KB

    wconv<<<dim3(34, 32), 256, 0, stream>>>(Wk, Wr, WT);
    init_k<<<896, 256, 0, stream>>>((uint4*)ws, inputs, x0F);

    dim3 cgrid(32, 8);   // (panel, rtile) -> XCD = panel%8
    _Float16 *hc = hF0, *hn = hF1;

    for (int t = 0; t < TT; ++t) {
        const _Float16* xF = (t & 1) ? x1F : x0F;
        _Float16* xnF = (t & 1) ? x0F : x1F;
        const float* xnext = (t < TT - 1) ? (inputs + (size_t)(t + 1) * FF) : nullptr;
        lstm_cell_mfma<<<cgrid, 512, 0, stream>>>(xF, hc, hn, cb, WT, bias, xnext, xnF);
        _Float16* tp = hc; hc = hn; hn = tp;
    }

    dense_out<<<BATCH, 256, 0, stream>>>(hc, Wd, bd, prF, out);

    for (int s = 1; s < OS; ++s) {
        lstm_cell_mfma<<<cgrid, 512, 0, stream>>>(prF, hc, hn, cb, WT, bias, nullptr, nullptr);
        _Float16* tp = hc; hc = hn; hn = tp;
        dense_out<<<BATCH, 256, 0, stream>>>(hc, Wd, bd, prF, out + (size_t)s * FF);
    }
}

// Round 8
// 2695.800 us; speedup vs baseline: 6.6599x; 1.0227x over previous
//
#include <hip/hip_runtime.h>
#include <math.h>

#define BATCH 512
#define TT    128
#define FF    64
#define UU    1024
#define ZZ    4096
#define OS    32
#define KTOT  1088
#define NCH   17            // K chunks of 64 (chunk 0 = x, 1..16 = h)
#define CROW  72            // A LDS row stride in f16 (64 + 8 pad = 144 B)
#define CBUF  (64 * CROW)   // 4608 f16 = 9216 B per A chunk buffer
#define NKB   68            // k16 blocks per n-tile (1088/16)

typedef _Float16 f16x8 __attribute__((ext_vector_type(8)));
typedef float f32x16 __attribute__((ext_vector_type(16)));

__device__ __forceinline__ float sigf(float x) { return 1.0f / (1.0f + expf(-x)); }

// ---------------------------------------------------------------------------
// W precompute: [Wk;Wr] (1088x4096 fp32) -> f16, gate-interleaved n' = 4u+g,
// FRAGMENT-LINEAR layout: block (nt, b) of 512 f16 at ((nt*68 + b)*512),
// holding B-frag for n-rows nt*32..+32, k16 window b: elem (lane, j) with
// lane = ((k>>3)&1)*32 + (n&31), j = k&7.  Block = 1 KB = one wave 16B/lane load.
// ---------------------------------------------------------------------------
__global__ __launch_bounds__(256) void wconv(
    const float* __restrict__ Wk, const float* __restrict__ Wr,
    _Float16* __restrict__ WT)
{
    __shared__ float T[32][129];
    const int k0 = blockIdx.x * 32;   // 34
    const int n0 = blockIdx.y * 128;  // 32
    const int u0 = n0 >> 2;
    const int t = threadIdx.x;
    #pragma unroll
    for (int i = 0; i < 16; ++i) {
        int idx = t + i * 256;
        int u = idx & 31, k = (idx >> 5) & 31, g = idx >> 10;
        int krow = k0 + k;
        int col = g * UU + u0 + u;
        float wv = (krow < FF) ? Wk[(size_t)krow * ZZ + col]
                               : Wr[(size_t)(krow - FF) * ZZ + col];
        T[k][u * 4 + g] = wv;
    }
    __syncthreads();
    #pragma unroll
    for (int i = 0; i < 16; ++i) {
        int idx = t + i * 256;
        int k = idx & 31, np = idx >> 5;
        int r = n0 + np;              // global n' row
        int kk = k0 + k;              // global k
        size_t o = ((size_t)(r >> 5) * NKB + (kk >> 4)) * 512
                 + (size_t)((((kk >> 3) & 1) * 32 + (r & 31)) * 8 + (kk & 7));
        WT[o] = (_Float16)T[k][np];
    }
}

// ---------------------------------------------------------------------------
// init: zero hF0 + c (3MB contiguous), convert x_0 to f16
// ---------------------------------------------------------------------------
__global__ __launch_bounds__(256) void init_k(
    uint4* __restrict__ zbase, const float* __restrict__ x0,
    _Float16* __restrict__ xF)
{
    const int b = blockIdx.x, t = threadIdx.x;
    if (b < 768) {
        zbase[(size_t)b * 256 + t] = make_uint4(0u, 0u, 0u, 0u);
    } else {
        int e = (b - 768) * 256 + t;   // 0..32767
        int bb = e >> 6, f = e & 63;
        xF[e] = (_Float16)x0[(size_t)bb * (TT * FF) + f];
    }
}

// ---------------------------------------------------------------------------
// Fused LSTM cell step: f16 GEMM on 32x32x16 MFMA.
// A: register-staged LDS double-buffer (raw s_barrier + lgkmcnt-only wait).
// W: direct global->VGPR, fragment-linear 1KB coalesced loads, 3-slot
//    cyclic register pipeline (depth-2 prefetch) -> no LDS round-trip.
// Block: 512 thr = 8 waves (mw=w>>2, nw=w&3); tile BM=64 x BN'=128, BK=64.
// Grid (32 panels, 8 rtiles); XCD = panel%8.
// ---------------------------------------------------------------------------
__global__ __launch_bounds__(512, 2) void lstm_cell_mfma(
    const _Float16* __restrict__ xF,      // [512][64]
    const _Float16* __restrict__ hF,      // [512][1024]
    _Float16* __restrict__ hFo,           // [512][1024]
    float* __restrict__ c,                // [512][1024] in-place
    const _Float16* __restrict__ WT,      // fragment-linear, see wconv
    const float* __restrict__ bias,       // [4096] natural order
    const float* __restrict__ xnext, _Float16* __restrict__ xnF)
{
    __shared__ __align__(16) char smem[64 * 132 * 4];   // 33792 B
    _Float16* lds = (_Float16*)smem;                    // A staging: 2 x CBUF
    float* z = (float*)smem;                            // epilogue overlay

    const int t = threadIdx.x;
    const int lane = t & 63;
    const int w  = t >> 6;
    const int mw = w >> 2;          // 0..1
    const int nw = w & 3;           // 0..3
    const int n0 = blockIdx.x * 128;
    const int r0 = blockIdx.y * 64;
    const int u0 = n0 >> 2;
    const int l31 = lane & 31;

    // ---- A staging: thread t owns row t>>3, 16B seg t&7 ----
    const int srow = t >> 3;        // 0..63
    const int sseg = t & 7;         // 0..7
    const _Float16* aAx = xF + (size_t)(r0 + srow) * FF + sseg * 8;
    const _Float16* aAh = hF + (size_t)(r0 + srow) * UU + sseg * 8;
    const int wA = srow * CROW + sseg * 8;
    uint4 sA[2];                    // chunk c lives in slot c&1

    // ---- W direct: wave nw reads n-tile (blockIdx.x*4 + nw) ----
    const _Float16* pW = WT + ((size_t)(blockIdx.x * 4 + nw) * NKB) * 512 + lane * 8;

    // ---- A fragment read offset (row mw*32 + l31, k-half by lane>>5) ----
    const int fra = (mw * 32 + l31) * CROW + (lane >> 5) * 8;

    f32x16 acc;
    #pragma unroll
    for (int i = 0; i < 16; ++i) acc[i] = 0.f;

    f16x8 wf[3][4];                 // 3-slot cyclic W pipeline

#define LOADA(ch)                                                              \
    {                                                                          \
        sA[(ch) & 1] = ((ch) == 0) ? *(const uint4*)aAx                        \
                                   : *(const uint4*)(aAh + ((ch) - 1) * 64);   \
    }
#define LOADW(ch)                                                              \
    {                                                                          \
        _Pragma("unroll")                                                      \
        for (int s = 0; s < 4; ++s)                                            \
            wf[(ch) % 3][s] = *(const f16x8*)(pW + ((ch) * 4 + s) * 512);      \
    }
#define WRITEA(ch)                                                             \
    {                                                                          \
        *(uint4*)(lds + ((ch) & 1) * CBUF + wA) = sA[(ch) & 1];                \
    }

    LOADA(0)
    LOADW(0)
    LOADA(1)
    LOADW(1)
    WRITEA(0)

    #pragma unroll
    for (int ch = 0; ch < NCH; ++ch) {
        if (ch + 2 < NCH) { LOADA(ch + 2) LOADW(ch + 2) }
        // lgkmcnt(0) only: own ds ops drained; vm loads stay in flight.
        __builtin_amdgcn_s_waitcnt(0xC07F);
        __builtin_amdgcn_s_barrier();
        if (ch + 1 < NCH) WRITEA(ch + 1)
        const _Float16* b = lds + (ch & 1) * CBUF;
        #pragma unroll
        for (int s = 0; s < 4; ++s) {
            f16x8 af = *(const f16x8*)(b + fra + s * 16);
            acc = __builtin_amdgcn_mfma_f32_32x32x16_f16(af, wf[ch % 3][s], acc, 0, 0, 0);
        }
    }
#undef LOADA
#undef LOADW
#undef WRITEA

    __syncthreads();   // full drain before z overlays the staging buffers

    // ---- C-frag (32x32: col=lane&31, row=(r&3)+8*(r>>2)+4*(lane>>5)) -> z ----
    {
        const int nloc = nw * 32 + l31;             // n' local = 4u+g
        const int gs = (nloc & 3) * 33 + (nloc >> 2);
        const int rbase = mw * 32 + 4 * (lane >> 5);
        #pragma unroll
        for (int r = 0; r < 16; ++r) {
            int m = rbase + (r & 3) + 8 * (r >> 2);
            z[m * 132 + gs] = acc[r];
        }
    }
    __syncthreads();

    // ---- gates: thread (u = t&31), 4 m-rows each ----
    {
        const int ul = t & 31;
        const int uu = u0 + ul;
        const float bi = bias[uu], bfr = bias[UU + uu];
        const float bg = bias[2 * UU + uu], bo = bias[3 * UU + uu];
        #pragma unroll
        for (int rep = 0; rep < 4; ++rep) {
            int m = (t >> 5) * 4 + rep;
            float zi = z[m * 132 + ul];
            float zf = z[m * 132 + 33 + ul];
            float zg = z[m * 132 + 66 + ul];
            float zo = z[m * 132 + 99 + ul];
            size_t idx = (size_t)(r0 + m) * UU + uu;
            float cn = sigf(zf + bfr) * c[idx] + sigf(zi + bi) * tanhf(zg + bg);
            c[idx] = cn;
            hFo[idx] = (_Float16)(sigf(zo + bo) * tanhf(cn));
        }
    }

    // ---- convert next warmup x slice (256 blocks x 128 = 32768 elems) ----
    if (xnext != nullptr && t < 128) {
        int e = (blockIdx.x + 32 * blockIdx.y) * 128 + t;
        int bb = e >> 6, f = e & 63;
        xnF[e] = (_Float16)xnext[(size_t)bb * (TT * FF) + f];
    }
}

// ---------------------------------------------------------------------------
// pred = h @ Wd + bd ; writes fp32 out slice + pred as f16
// ---------------------------------------------------------------------------
__global__ __launch_bounds__(256) void dense_out(
    const _Float16* __restrict__ hF,
    const float* __restrict__ Wd, const float* __restrict__ bd,
    _Float16* __restrict__ pF, float* __restrict__ outp)
{
    __shared__ float red[4][64];
    const int t = threadIdx.x, f = t & 63, ks = t >> 6, bb = blockIdx.x;
    const f16x8* hr = (const f16x8*)(hF + (size_t)bb * UU + ks * 256);
    const float* wp = Wd + (size_t)(ks * 256) * FF + f;
    float s = 0.f;
    #pragma unroll 4
    for (int v = 0; v < 32; ++v) {
        f16x8 a = hr[v];
        #pragma unroll
        for (int j = 0; j < 8; ++j)
            s += (float)a[j] * wp[(size_t)(v * 8 + j) * FF];
    }
    red[ks][f] = s;
    __syncthreads();
    if (ks == 0) {
        float vv = red[0][f] + red[1][f] + red[2][f] + red[3][f] + bd[f];
        outp[(size_t)bb * (OS * FF) + f] = vv;
        pF[bb * FF + f] = (_Float16)vv;
    }
}

extern "C" void kernel_launch(void* const* d_in, const int* in_sizes, int n_in,
                              void* d_out, int out_size, void* d_ws, size_t ws_size,
                              hipStream_t stream) {
    const float* inputs = (const float*)d_in[0];
    const float* Wk     = (const float*)d_in[1];
    const float* Wr     = (const float*)d_in[2];
    const float* bias   = (const float*)d_in[3];
    const float* Wd     = (const float*)d_in[4];
    const float* bd     = (const float*)d_in[5];
    float* out = (float*)d_out;

    char* ws = (char*)d_ws;
    _Float16* hF0 = (_Float16*)(ws);                  // 1 MB   (zeroed)
    float*    cb  = (float*)(ws + 1048576);           // 2 MB   (zeroed)
    _Float16* hF1 = (_Float16*)(ws + 3145728);        // 1 MB
    _Float16* WT  = (_Float16*)(ws + 4194304);        // 8,912,896 B (fragment-linear)
    _Float16* x0F = (_Float16*)(ws + 13107200);       // 64 KB
    _Float16* x1F = (_Float16*)(ws + 13172736);       // 64 KB
    _Float16* prF = (_Float16*)(ws + 13238272);       // 64 KB

    wconv<<<dim3(34, 32), 256, 0, stream>>>(Wk, Wr, WT);
    init_k<<<896, 256, 0, stream>>>((uint4*)ws, inputs, x0F);

    dim3 cgrid(32, 8);   // (panel, rtile) -> XCD = panel%8
    _Float16 *hc = hF0, *hn = hF1;

    for (int t = 0; t < TT; ++t) {
        const _Float16* xF = (t & 1) ? x1F : x0F;
        _Float16* xnF = (t & 1) ? x0F : x1F;
        const float* xnext = (t < TT - 1) ? (inputs + (size_t)(t + 1) * FF) : nullptr;
        lstm_cell_mfma<<<cgrid, 512, 0, stream>>>(xF, hc, hn, cb, WT, bias, xnext, xnF);
        _Float16* tp = hc; hc = hn; hn = tp;
    }

    dense_out<<<BATCH, 256, 0, stream>>>(hc, Wd, bd, prF, out);

    for (int s = 1; s < OS; ++s) {
        lstm_cell_mfma<<<cgrid, 512, 0, stream>>>(prF, hc, hn, cb, WT, bias, nullptr, nullptr);
        _Float16* tp = hc; hc = hn; hn = tp;
        dense_out<<<BATCH, 256, 0, stream>>>(hc, Wd, bd, prF, out + (size_t)s * FF);
    }
}